// Round 3
// baseline (431.520 us; speedup 1.0000x reference)
//
#include <hip/hip_runtime.h>
#include <hip/hip_bf16.h>

#define N_NODES 50000
#define N_EDGES 800000
#define D 64

// ---------- helpers ----------
__device__ __forceinline__ float b2f(unsigned short h) {
    return __uint_as_float(((unsigned)h) << 16);
}
__device__ __forceinline__ unsigned short f2b(float f) {
    __hip_bfloat16 t = __float2bfloat16(f);
    return *reinterpret_cast<unsigned short*>(&t);
}

// ---------- kernel 0: runtime dtype / index-width detection ----------
// flags[0] = 1 if float tensors are fp32 (else bf16); flags[1] = 1 if idx int64
__global__ void detect_mode(const void* feat, const void* srcv, unsigned* flags) {
    const int t = threadIdx.x;          // 128 threads = 2 waves
    if (t < 64) {
        const unsigned short* p = (const unsigned short*)feat;
        float x = b2f(p[2 * t]);
        float a = fabsf(x);
        bool insane = !(a <= 64.f) || (x != 0.f && a < 9.3132e-10f);
        unsigned long long m = __ballot(insane);
        if (t == 0) flags[0] = (__popcll(m) >= 8) ? 1u : 0u;
    } else {
        const int* s32 = (const int*)srcv;
        int v = s32[2 * (t - 64) + 1];
        unsigned long long m = __ballot(v == 0);
        if (t == 64) flags[1] = (__popcll(m) >= 32) ? 1u : 0u;
    }
}

// ---------- kernel 1: T = feat @ W_theta -> d_out ----------
__global__ __launch_bounds__(256, 2)
void node_theta(const void* __restrict__ featv, const void* __restrict__ Wtv,
                const unsigned* __restrict__ flags, void* __restrict__ outv) {
    const unsigned fp32mode = flags[0];
    const int lane = threadIdx.x & 63;
    const int wid  = threadIdx.x >> 6;

    float wt[D];
    if (fp32mode) {
        const float* W = (const float*)Wtv;
#pragma unroll
        for (int k = 0; k < D; ++k) wt[k] = W[k * D + lane];
    } else {
        const unsigned short* W = (const unsigned short*)Wtv;
#pragma unroll
        for (int k = 0; k < D; ++k) wt[k] = b2f(W[k * D + lane]);
    }

    const int nW = gridDim.x << 2;
    for (int r = (blockIdx.x << 2) + wid; r < N_NODES; r += nW) {
        float x = fp32mode ? ((const float*)featv)[r * D + lane]
                           : b2f(((const unsigned short*)featv)[r * D + lane]);
        float at = 0.f;
#pragma unroll
        for (int k = 0; k < D; ++k)
            at = fmaf(__shfl(x, k, 64), wt[k], at);
        if (fp32mode) ((float*)outv)[r * D + lane] = at;
        else          ((unsigned short*)outv)[r * D + lane] = f2b(at);
    }
}

// ---------- kernel 2: histogram of dst ----------
__global__ __launch_bounds__(256)
void histogram(const void* __restrict__ dstv, const unsigned* __restrict__ flags,
               unsigned* __restrict__ counts) {
    const int e = blockIdx.x * 256 + threadIdx.x;      // grid exact: 3125*256
    int d = flags[1] ? (int)((const long long*)dstv)[e] : ((const int*)dstv)[e];
    d = min(max(d, 0), N_NODES - 1);
    atomicAdd(&counts[d], 1u);
}

// ---------- kernel 3: exclusive scan of counts -> offsets, cursor ----------
// single block, 1024 threads; counts aliases cursor (read-then-overwrite per-slot)
#define CHUNK 49   // 1024*49 = 50176 >= N_NODES
__global__ __launch_bounds__(1024)
void scan_counts(unsigned* __restrict__ counts /*==cursor*/,
                 unsigned* __restrict__ offsets, unsigned* __restrict__ cursor) {
    __shared__ unsigned part[1024];
    const int t = threadIdx.x;
    const int base = t * CHUNK;
    unsigned s = 0;
    for (int i = 0; i < CHUNK; ++i) {
        int idx = base + i;
        if (idx < N_NODES) s += counts[idx];
    }
    part[t] = s;
    __syncthreads();
    for (int off = 1; off < 1024; off <<= 1) {         // Hillis-Steele inclusive
        unsigned v = (t >= off) ? part[t - off] : 0u;
        __syncthreads();
        part[t] += v;
        __syncthreads();
    }
    unsigned excl = (t == 0) ? 0u : part[t - 1];
    for (int i = 0; i < CHUNK; ++i) {
        int idx = base + i;
        if (idx < N_NODES) {
            unsigned c = counts[idx];                   // read before overwrite
            offsets[idx] = excl;
            cursor[idx]  = excl;
            excl += c;
        }
    }
    if (t == 0) offsets[N_NODES] = N_EDGES;
}

// ---------- kernel 4: scatter src ids into dst buckets ----------
__global__ __launch_bounds__(256)
void scatter_edges(const void* __restrict__ srcv, const void* __restrict__ dstv,
                   const unsigned* __restrict__ flags,
                   unsigned* __restrict__ cursor, unsigned* __restrict__ esrc) {
    const int e = blockIdx.x * 256 + threadIdx.x;      // grid exact
    int s, d;
    if (flags[1]) {
        s = (int)((const long long*)srcv)[e];
        d = (int)((const long long*)dstv)[e];
    } else {
        s = ((const int*)srcv)[e];
        d = ((const int*)dstv)[e];
    }
    s = min(max(s, 0), N_NODES - 1);
    d = min(max(d, 0), N_NODES - 1);
    unsigned pos = atomicAdd(&cursor[d], 1u);
    esrc[pos] = (unsigned)s;
}

// ---------- kernel 5: per-node segmented min over gathered T rows ----------
__global__ __launch_bounds__(256)
void min_gather(const unsigned* __restrict__ offsets, const unsigned* __restrict__ esrc,
                const void* __restrict__ outv /*T*/, const unsigned* __restrict__ flags,
                unsigned short* __restrict__ Mb) {
    const unsigned fp32mode = flags[0];
    const int lane = threadIdx.x & 63;
    const int wid  = threadIdx.x >> 6;
    const int n = (blockIdx.x << 2) + wid;             // grid exact: 12500*4 waves
    int a = (int)offsets[n];
    const int b = (int)offsets[n + 1];
    float m = __uint_as_float(0x7f7fffffu);            // +FLT_MAX; deg>=1 (self-loop)
    const float* Tf = (const float*)outv;
    const unsigned short* Th = (const unsigned short*)outv;
    for (; a + 1 < b; a += 2) {                        // 2-way unroll for ILP
        int s0 = (int)esrc[a], s1 = (int)esrc[a + 1];
        float v0 = fp32mode ? Tf[s0 * D + lane] : b2f(Th[s0 * D + lane]);
        float v1 = fp32mode ? Tf[s1 * D + lane] : b2f(Th[s1 * D + lane]);
        m = fminf(m, fminf(v0, v1));
    }
    if (a < b) {
        int s0 = (int)esrc[a];
        float v0 = fp32mode ? Tf[s0 * D + lane] : b2f(Th[s0 * D + lane]);
        m = fminf(m, v0);
    }
    Mb[n * D + lane] = f2b(m);   // bf16 min is exact in bf16 mode (real mode)
}

// ---------- kernel 6: out = feat@Wt + feat@Wp + bt + bp - min ----------
__global__ __launch_bounds__(256, 2)
void finalize(const void* __restrict__ featv,
              const void* __restrict__ Wtv, const void* __restrict__ btv,
              const void* __restrict__ Wpv, const void* __restrict__ bpv,
              const unsigned* __restrict__ flags,
              const unsigned short* __restrict__ Mb, void* __restrict__ outv) {
    const unsigned fp32mode = flags[0];
    const int lane = threadIdx.x & 63;
    const int wid  = threadIdx.x >> 6;

    float wt[D], wp[D], bsum;
    if (fp32mode) {
        const float* Wt = (const float*)Wtv;
        const float* Wp = (const float*)Wpv;
#pragma unroll
        for (int k = 0; k < D; ++k) { wt[k] = Wt[k * D + lane]; wp[k] = Wp[k * D + lane]; }
        bsum = ((const float*)btv)[lane] + ((const float*)bpv)[lane];
    } else {
        const unsigned short* Wt = (const unsigned short*)Wtv;
        const unsigned short* Wp = (const unsigned short*)Wpv;
#pragma unroll
        for (int k = 0; k < D; ++k) { wt[k] = b2f(Wt[k * D + lane]); wp[k] = b2f(Wp[k * D + lane]); }
        bsum = b2f(((const unsigned short*)btv)[lane]) + b2f(((const unsigned short*)bpv)[lane]);
    }

    const int nW = gridDim.x << 2;
    for (int r = (blockIdx.x << 2) + wid; r < N_NODES; r += nW) {
        float x = fp32mode ? ((const float*)featv)[r * D + lane]
                           : b2f(((const unsigned short*)featv)[r * D + lane]);
        float at = 0.f, ap = 0.f;
#pragma unroll
        for (int k = 0; k < D; ++k) {
            float f = __shfl(x, k, 64);
            at = fmaf(f, wt[k], at);
            ap = fmaf(f, wp[k], ap);
        }
        float res = at + ap + bsum - b2f(Mb[r * D + lane]);
        if (fp32mode) ((float*)outv)[r * D + lane] = res;
        else          ((unsigned short*)outv)[r * D + lane] = f2b(res);
    }
}

extern "C" void kernel_launch(void* const* d_in, const int* in_sizes, int n_in,
                              void* d_out, int out_size, void* d_ws, size_t ws_size,
                              hipStream_t stream) {
    // ws layout (total ~10.0 MB; known-safe budget <= 12.8 MB):
    char* p = (char*)d_ws;
    unsigned*       flags   = (unsigned*)p;                         // 256 B
    unsigned*       offsets = (unsigned*)(p + 256);                 // 50016*4
    unsigned*       cursor  = (unsigned*)(p + 256 + 200064);        // 50016*4 (counts first)
    unsigned*       esrc    = (unsigned*)(p + 256 + 2 * 200064);    // 800000*4
    unsigned short* Mb      = (unsigned short*)(p + 256 + 2 * 200064 + 3200000); // 6.4 MB

    detect_mode<<<1, 128, 0, stream>>>(d_in[0], d_in[1], flags);
    node_theta<<<1024, 256, 0, stream>>>(d_in[0], d_in[3], flags, d_out);
    hipMemsetAsync(cursor, 0, (size_t)N_NODES * sizeof(unsigned), stream);
    histogram<<<N_EDGES / 256, 256, 0, stream>>>(d_in[2], flags, cursor);
    scan_counts<<<1, 1024, 0, stream>>>(cursor, offsets, cursor);
    scatter_edges<<<N_EDGES / 256, 256, 0, stream>>>(d_in[1], d_in[2], flags, cursor, esrc);
    min_gather<<<N_NODES / 4, 256, 0, stream>>>(offsets, esrc, d_out, flags, Mb);
    finalize<<<1024, 256, 0, stream>>>(d_in[0], d_in[3], d_in[4], d_in[5], d_in[6],
                                       flags, Mb, d_out);
}

// Round 4
// 314.179 us; speedup vs baseline: 1.3735x; 1.3735x over previous
//
#include <hip/hip_runtime.h>
#include <hip/hip_bf16.h>

#define N_NODES 50000
#define N_EDGES 800000
#define D 64
#define NPART 196   // ceil(50000/256)

// ---------- helpers ----------
__device__ __forceinline__ float b2f(unsigned short h) {
    return __uint_as_float(((unsigned)h) << 16);
}
__device__ __forceinline__ unsigned short f2b(float f) {
    __hip_bfloat16 t = __float2bfloat16(f);
    return *reinterpret_cast<unsigned short*>(&t);
}

// ---------- kernel 0: runtime dtype / index-width detection ----------
__global__ void detect_mode(const void* feat, const void* srcv, unsigned* flags) {
    const int t = threadIdx.x;          // 128 threads = 2 waves
    if (t < 64) {
        const unsigned short* p = (const unsigned short*)feat;
        float x = b2f(p[2 * t]);
        float a = fabsf(x);
        bool insane = !(a <= 64.f) || (x != 0.f && a < 9.3132e-10f);
        unsigned long long m = __ballot(insane);
        if (t == 0) flags[0] = (__popcll(m) >= 8) ? 1u : 0u;
    } else {
        const int* s32 = (const int*)srcv;
        int v = s32[2 * (t - 64) + 1];
        unsigned long long m = __ballot(v == 0);
        if (t == 64) flags[1] = (__popcll(m) >= 32) ? 1u : 0u;
    }
}

// ---------- kernel 1: T = feat @ W_theta -> d_out ----------
__global__ __launch_bounds__(256, 2)
void node_theta(const void* __restrict__ featv, const void* __restrict__ Wtv,
                const unsigned* __restrict__ flags, void* __restrict__ outv) {
    const unsigned fp32mode = flags[0];
    const int lane = threadIdx.x & 63;
    const int wid  = threadIdx.x >> 6;

    float wt[D];
    if (fp32mode) {
        const float* W = (const float*)Wtv;
#pragma unroll
        for (int k = 0; k < D; ++k) wt[k] = W[k * D + lane];
    } else {
        const unsigned short* W = (const unsigned short*)Wtv;
#pragma unroll
        for (int k = 0; k < D; ++k) wt[k] = b2f(W[k * D + lane]);
    }

    const int nW = gridDim.x << 2;
    for (int r = (blockIdx.x << 2) + wid; r < N_NODES; r += nW) {
        float x = fp32mode ? ((const float*)featv)[r * D + lane]
                           : b2f(((const unsigned short*)featv)[r * D + lane]);
        float at = 0.f;
#pragma unroll
        for (int k = 0; k < D; ++k)
            at = fmaf(__shfl(x, k, 64), wt[k], at);
        if (fp32mode) ((float*)outv)[r * D + lane] = at;
        else          ((unsigned short*)outv)[r * D + lane] = f2b(at);
    }
}

// ---------- kernel 2: histogram of dst ----------
__global__ __launch_bounds__(256)
void histogram(const void* __restrict__ dstv, const unsigned* __restrict__ flags,
               unsigned* __restrict__ counts) {
    const int e = blockIdx.x * 256 + threadIdx.x;      // grid exact: 3125*256
    int d = flags[1] ? (int)((const long long*)dstv)[e] : ((const int*)dstv)[e];
    d = min(max(d, 0), N_NODES - 1);
    atomicAdd(&counts[d], 1u);
}

// ---------- two-level scan (replaces 125us single-block scan) ----------
// 3a: per-block sums of counts
__global__ __launch_bounds__(256)
void block_sums(const unsigned* __restrict__ counts, unsigned* __restrict__ partials) {
    __shared__ unsigned wsum[4];
    const int idx = blockIdx.x * 256 + threadIdx.x;
    unsigned c = (idx < N_NODES) ? counts[idx] : 0u;
#pragma unroll
    for (int off = 32; off; off >>= 1) c += __shfl_down(c, off, 64);
    if ((threadIdx.x & 63) == 0) wsum[threadIdx.x >> 6] = c;
    __syncthreads();
    if (threadIdx.x == 0)
        partials[blockIdx.x] = wsum[0] + wsum[1] + wsum[2] + wsum[3];
}

// 3b: exclusive scan of NPART partials (single tiny block)
__global__ __launch_bounds__(256)
void scan_partials(unsigned* __restrict__ partials) {
    __shared__ unsigned sm[256];
    const int t = threadIdx.x;
    unsigned v = (t < NPART) ? partials[t] : 0u;
    sm[t] = v;
    __syncthreads();
    for (int off = 1; off < 256; off <<= 1) {
        unsigned u = (t >= off) ? sm[t - off] : 0u;
        __syncthreads();
        sm[t] += u;
        __syncthreads();
    }
    if (t < NPART) partials[t] = sm[t] - v;            // exclusive
}

// 3c: block-local scan + base -> offsets, cursor (counts aliases cursor: read-once-then-write)
__global__ __launch_bounds__(256)
void write_offsets(const unsigned* __restrict__ counts, const unsigned* __restrict__ partials,
                   unsigned* __restrict__ offsets, unsigned* __restrict__ cursor) {
    __shared__ unsigned sm[256];
    const int t = threadIdx.x;
    const int idx = blockIdx.x * 256 + t;
    unsigned c = (idx < N_NODES) ? counts[idx] : 0u;   // single global read of counts
    sm[t] = c;
    __syncthreads();
    for (int off = 1; off < 256; off <<= 1) {
        unsigned u = (t >= off) ? sm[t - off] : 0u;
        __syncthreads();
        sm[t] += u;
        __syncthreads();
    }
    if (idx < N_NODES) {
        unsigned excl = partials[blockIdx.x] + sm[t] - c;
        offsets[idx] = excl;
        cursor[idx]  = excl;
    }
    if (idx == 0) offsets[N_NODES] = N_EDGES;
}

// ---------- kernel 4: scatter src ids into dst buckets ----------
__global__ __launch_bounds__(256)
void scatter_edges(const void* __restrict__ srcv, const void* __restrict__ dstv,
                   const unsigned* __restrict__ flags,
                   unsigned* __restrict__ cursor, unsigned* __restrict__ esrc) {
    const int e = blockIdx.x * 256 + threadIdx.x;      // grid exact
    int s, d;
    if (flags[1]) {
        s = (int)((const long long*)srcv)[e];
        d = (int)((const long long*)dstv)[e];
    } else {
        s = ((const int*)srcv)[e];
        d = ((const int*)dstv)[e];
    }
    s = min(max(s, 0), N_NODES - 1);
    d = min(max(d, 0), N_NODES - 1);
    unsigned pos = atomicAdd(&cursor[d], 1u);
    esrc[pos] = (unsigned)s;
}

// ---------- kernel 5: per-node segmented min over gathered T rows ----------
__global__ __launch_bounds__(256)
void min_gather(const unsigned* __restrict__ offsets, const unsigned* __restrict__ esrc,
                const void* __restrict__ outv /*T*/, const unsigned* __restrict__ flags,
                unsigned short* __restrict__ Mb) {
    const unsigned fp32mode = flags[0];
    const int lane = threadIdx.x & 63;
    const int wid  = threadIdx.x >> 6;
    const int n = (blockIdx.x << 2) + wid;             // grid exact: 12500*4 waves
    int a = (int)offsets[n];
    const int b = (int)offsets[n + 1];
    float m = __uint_as_float(0x7f7fffffu);            // +FLT_MAX; deg>=1 (self-loop)
    const float* Tf = (const float*)outv;
    const unsigned short* Th = (const unsigned short*)outv;
    for (; a + 1 < b; a += 2) {                        // 2-way unroll for ILP
        int s0 = (int)esrc[a], s1 = (int)esrc[a + 1];
        float v0 = fp32mode ? Tf[s0 * D + lane] : b2f(Th[s0 * D + lane]);
        float v1 = fp32mode ? Tf[s1 * D + lane] : b2f(Th[s1 * D + lane]);
        m = fminf(m, fminf(v0, v1));
    }
    if (a < b) {
        int s0 = (int)esrc[a];
        float v0 = fp32mode ? Tf[s0 * D + lane] : b2f(Th[s0 * D + lane]);
        m = fminf(m, v0);
    }
    Mb[n * D + lane] = f2b(m);   // bf16 min is exact in bf16 mode (real mode)
}

// ---------- kernel 6: out = feat@Wt + feat@Wp + bt + bp - min ----------
__global__ __launch_bounds__(256, 2)
void finalize(const void* __restrict__ featv,
              const void* __restrict__ Wtv, const void* __restrict__ btv,
              const void* __restrict__ Wpv, const void* __restrict__ bpv,
              const unsigned* __restrict__ flags,
              const unsigned short* __restrict__ Mb, void* __restrict__ outv) {
    const unsigned fp32mode = flags[0];
    const int lane = threadIdx.x & 63;
    const int wid  = threadIdx.x >> 6;

    float wt[D], wp[D], bsum;
    if (fp32mode) {
        const float* Wt = (const float*)Wtv;
        const float* Wp = (const float*)Wpv;
#pragma unroll
        for (int k = 0; k < D; ++k) { wt[k] = Wt[k * D + lane]; wp[k] = Wp[k * D + lane]; }
        bsum = ((const float*)btv)[lane] + ((const float*)bpv)[lane];
    } else {
        const unsigned short* Wt = (const unsigned short*)Wtv;
        const unsigned short* Wp = (const unsigned short*)Wpv;
#pragma unroll
        for (int k = 0; k < D; ++k) { wt[k] = b2f(Wt[k * D + lane]); wp[k] = b2f(Wp[k * D + lane]); }
        bsum = b2f(((const unsigned short*)btv)[lane]) + b2f(((const unsigned short*)bpv)[lane]);
    }

    const int nW = gridDim.x << 2;
    for (int r = (blockIdx.x << 2) + wid; r < N_NODES; r += nW) {
        float x = fp32mode ? ((const float*)featv)[r * D + lane]
                           : b2f(((const unsigned short*)featv)[r * D + lane]);
        float at = 0.f, ap = 0.f;
#pragma unroll
        for (int k = 0; k < D; ++k) {
            float f = __shfl(x, k, 64);
            at = fmaf(f, wt[k], at);
            ap = fmaf(f, wp[k], ap);
        }
        float res = at + ap + bsum - b2f(Mb[r * D + lane]);
        if (fp32mode) ((float*)outv)[r * D + lane] = res;
        else          ((unsigned short*)outv)[r * D + lane] = f2b(res);
    }
}

extern "C" void kernel_launch(void* const* d_in, const int* in_sizes, int n_in,
                              void* d_out, int out_size, void* d_ws, size_t ws_size,
                              hipStream_t stream) {
    // ws layout (~9.6 MB; known-safe budget <= 12.8 MB):
    char* p = (char*)d_ws;
    unsigned*       flags    = (unsigned*)p;                          // 256 B
    unsigned*       offsets  = (unsigned*)(p + 256);                  // 50016*4
    unsigned*       cursor   = (unsigned*)(p + 256 + 200064);         // 50016*4 (counts first)
    unsigned*       esrc     = (unsigned*)(p + 256 + 2 * 200064);     // 800000*4
    unsigned short* Mb       = (unsigned short*)(p + 256 + 2 * 200064 + 3200000); // 6.4 MB
    unsigned*       partials = (unsigned*)(p + 256 + 2 * 200064 + 3200000 + 6400000); // 1 KB

    detect_mode<<<1, 128, 0, stream>>>(d_in[0], d_in[1], flags);
    node_theta<<<1024, 256, 0, stream>>>(d_in[0], d_in[3], flags, d_out);
    hipMemsetAsync(cursor, 0, (size_t)N_NODES * sizeof(unsigned), stream);
    histogram<<<N_EDGES / 256, 256, 0, stream>>>(d_in[2], flags, cursor);
    block_sums<<<NPART, 256, 0, stream>>>(cursor, partials);
    scan_partials<<<1, 256, 0, stream>>>(partials);
    write_offsets<<<NPART, 256, 0, stream>>>(cursor, partials, offsets, cursor);
    scatter_edges<<<N_EDGES / 256, 256, 0, stream>>>(d_in[1], d_in[2], flags, cursor, esrc);
    min_gather<<<N_NODES / 4, 256, 0, stream>>>(offsets, esrc, d_out, flags, Mb);
    finalize<<<1024, 256, 0, stream>>>(d_in[0], d_in[3], d_in[4], d_in[5], d_in[6],
                                       flags, Mb, d_out);
}

// Round 5
// 275.306 us; speedup vs baseline: 1.5674x; 1.1412x over previous
//
#include <hip/hip_runtime.h>
#include <hip/hip_bf16.h>

#define N_NODES 50000
#define N_EDGES 800000
#define D 64
#define NPART 196   // ceil(50000/256)
#define NSLOT 50016 // padded per-replica counter stride

// ---------- helpers ----------
__device__ __forceinline__ float b2f(unsigned short h) {
    return __uint_as_float(((unsigned)h) << 16);
}
__device__ __forceinline__ unsigned short f2b(float f) {
    __hip_bfloat16 t = __float2bfloat16(f);
    return *reinterpret_cast<unsigned short*>(&t);
}

// ---------- kernel 0: runtime dtype / index-width detection ----------
__global__ void detect_mode(const void* feat, const void* srcv, unsigned* flags) {
    const int t = threadIdx.x;          // 128 threads = 2 waves
    if (t < 64) {
        const unsigned short* p = (const unsigned short*)feat;
        float x = b2f(p[2 * t]);
        float a = fabsf(x);
        bool insane = !(a <= 64.f) || (x != 0.f && a < 9.3132e-10f);
        unsigned long long m = __ballot(insane);
        if (t == 0) flags[0] = (__popcll(m) >= 8) ? 1u : 0u;
    } else {
        const int* s32 = (const int*)srcv;
        int v = s32[2 * (t - 64) + 1];
        unsigned long long m = __ballot(v == 0);
        if (t == 64) flags[1] = (__popcll(m) >= 32) ? 1u : 0u;
    }
}

// ---------- kernel 1: T = feat @ W_theta -> d_out ----------
__global__ __launch_bounds__(256, 2)
void node_theta(const void* __restrict__ featv, const void* __restrict__ Wtv,
                const unsigned* __restrict__ flags, void* __restrict__ outv) {
    const unsigned fp32mode = flags[0];
    const int lane = threadIdx.x & 63;
    const int wid  = threadIdx.x >> 6;

    float wt[D];
    if (fp32mode) {
        const float* W = (const float*)Wtv;
#pragma unroll
        for (int k = 0; k < D; ++k) wt[k] = W[k * D + lane];
    } else {
        const unsigned short* W = (const unsigned short*)Wtv;
#pragma unroll
        for (int k = 0; k < D; ++k) wt[k] = b2f(W[k * D + lane]);
    }

    const int nW = gridDim.x << 2;
    for (int r = (blockIdx.x << 2) + wid; r < N_NODES; r += nW) {
        float x = fp32mode ? ((const float*)featv)[r * D + lane]
                           : b2f(((const unsigned short*)featv)[r * D + lane]);
        float at = 0.f;
#pragma unroll
        for (int k = 0; k < D; ++k)
            at = fmaf(__shfl(x, k, 64), wt[k], at);
        if (fp32mode) ((float*)outv)[r * D + lane] = at;
        else          ((unsigned short*)outv)[r * D + lane] = f2b(at);
    }
}

// ---------- kernel 2: 4-replica histogram of dst (contention /4) ----------
__global__ __launch_bounds__(256)
void histogram(const void* __restrict__ dstv, const unsigned* __restrict__ flags,
               unsigned* __restrict__ cnt4) {
    const int e = blockIdx.x * 256 + threadIdx.x;      // grid exact: 3125*256
    int d = flags[1] ? (int)((const long long*)dstv)[e] : ((const int*)dstv)[e];
    d = min(max(d, 0), N_NODES - 1);
    atomicAdd(&cnt4[(blockIdx.x & 3) * NSLOT + d], 1u);
}

// ---------- two-level scan ----------
__global__ __launch_bounds__(256)
void block_sums(const unsigned* __restrict__ cnt4, unsigned* __restrict__ partials) {
    __shared__ unsigned wsum[4];
    const int idx = blockIdx.x * 256 + threadIdx.x;
    unsigned c = 0;
    if (idx < N_NODES)
        c = cnt4[idx] + cnt4[NSLOT + idx] + cnt4[2 * NSLOT + idx] + cnt4[3 * NSLOT + idx];
#pragma unroll
    for (int off = 32; off; off >>= 1) c += __shfl_down(c, off, 64);
    if ((threadIdx.x & 63) == 0) wsum[threadIdx.x >> 6] = c;
    __syncthreads();
    if (threadIdx.x == 0)
        partials[blockIdx.x] = wsum[0] + wsum[1] + wsum[2] + wsum[3];
}

__global__ __launch_bounds__(256)
void scan_partials(unsigned* __restrict__ partials) {
    __shared__ unsigned sm[256];
    const int t = threadIdx.x;
    unsigned v = (t < NPART) ? partials[t] : 0u;
    sm[t] = v;
    __syncthreads();
    for (int off = 1; off < 256; off <<= 1) {
        unsigned u = (t >= off) ? sm[t - off] : 0u;
        __syncthreads();
        sm[t] += u;
        __syncthreads();
    }
    if (t < NPART) partials[t] = sm[t] - v;            // exclusive
}

// block-local scan + base -> offsets; seed 4 replica cursors (aliases cnt4:
// each thread reads its cnt4 slots once, then overwrites them)
__global__ __launch_bounds__(256)
void write_offsets(unsigned* __restrict__ cnt4, const unsigned* __restrict__ partials,
                   unsigned* __restrict__ offsets) {
    __shared__ unsigned sm[256];
    const int t = threadIdx.x;
    const int idx = blockIdx.x * 256 + t;
    unsigned c0 = 0, c1 = 0, c2 = 0, c3 = 0;
    if (idx < N_NODES) {
        c0 = cnt4[idx];
        c1 = cnt4[NSLOT + idx];
        c2 = cnt4[2 * NSLOT + idx];
        c3 = cnt4[3 * NSLOT + idx];
    }
    unsigned c = c0 + c1 + c2 + c3;
    sm[t] = c;
    __syncthreads();
    for (int off = 1; off < 256; off <<= 1) {
        unsigned u = (t >= off) ? sm[t - off] : 0u;
        __syncthreads();
        sm[t] += u;
        __syncthreads();
    }
    if (idx < N_NODES) {
        unsigned excl = partials[blockIdx.x] + sm[t] - c;
        offsets[idx] = excl;
        cnt4[idx]             = excl;                   // replica 0 cursor
        cnt4[NSLOT + idx]     = excl + c0;              // replica 1
        cnt4[2 * NSLOT + idx] = excl + c0 + c1;         // replica 2
        cnt4[3 * NSLOT + idx] = excl + c0 + c1 + c2;    // replica 3
    }
    if (idx == 0) offsets[N_NODES] = N_EDGES;
}

// ---------- kernel 4: scatter src ids into dst buckets (replica cursors) ----------
__global__ __launch_bounds__(256)
void scatter_edges(const void* __restrict__ srcv, const void* __restrict__ dstv,
                   const unsigned* __restrict__ flags,
                   unsigned* __restrict__ cursor4, unsigned* __restrict__ esrc) {
    const int e = blockIdx.x * 256 + threadIdx.x;      // grid exact
    int s, d;
    if (flags[1]) {
        s = (int)((const long long*)srcv)[e];
        d = (int)((const long long*)dstv)[e];
    } else {
        s = ((const int*)srcv)[e];
        d = ((const int*)dstv)[e];
    }
    s = min(max(s, 0), N_NODES - 1);
    d = min(max(d, 0), N_NODES - 1);
    unsigned pos = atomicAdd(&cursor4[(blockIdx.x & 3) * NSLOT + d], 1u);
    esrc[pos] = (unsigned)s;
}

// ---------- kernel 5: vectorized per-node segmented min ----------
// lane = (edge-group g = lane>>4, feature-quad fb = (lane&15)*4)
__global__ __launch_bounds__(256)
void min_gather(const unsigned* __restrict__ offsets, const unsigned* __restrict__ esrc,
                const void* __restrict__ outv /*T*/, const unsigned* __restrict__ flags,
                unsigned short* __restrict__ Mb) {
    const unsigned fp32mode = flags[0];
    const int lane = threadIdx.x & 63;
    const int wid  = threadIdx.x >> 6;
    const int n = (blockIdx.x << 2) + wid;             // grid exact: 12500*4 waves
    const int g  = lane >> 4;
    const int fb = (lane & 15) << 2;
    const int a = (int)offsets[n];
    const int b = (int)offsets[n + 1];
    const float FMAX = __uint_as_float(0x7f7fffffu);
    float m0 = FMAX, m1 = FMAX, m2 = FMAX, m3 = FMAX;

    int i = a + g;
    if (fp32mode) {
        const float* Tf = (const float*)outv;
        for (; i + 4 < b; i += 8) {                    // 2 gathers in flight
            int s0 = (int)esrc[i], s1 = (int)esrc[i + 4];
            float4 v0 = *(const float4*)(Tf + s0 * D + fb);
            float4 v1 = *(const float4*)(Tf + s1 * D + fb);
            m0 = fminf(m0, fminf(v0.x, v1.x));
            m1 = fminf(m1, fminf(v0.y, v1.y));
            m2 = fminf(m2, fminf(v0.z, v1.z));
            m3 = fminf(m3, fminf(v0.w, v1.w));
        }
        if (i < b) {
            int s0 = (int)esrc[i];
            float4 v0 = *(const float4*)(Tf + s0 * D + fb);
            m0 = fminf(m0, v0.x); m1 = fminf(m1, v0.y);
            m2 = fminf(m2, v0.z); m3 = fminf(m3, v0.w);
        }
    } else {
        const unsigned short* Th = (const unsigned short*)outv;
        for (; i + 4 < b; i += 8) {
            int s0 = (int)esrc[i], s1 = (int)esrc[i + 4];
            uint2 v0 = *(const uint2*)(Th + s0 * D + fb);
            uint2 v1 = *(const uint2*)(Th + s1 * D + fb);
            m0 = fminf(m0, fminf(b2f((unsigned short)v0.x), b2f((unsigned short)v1.x)));
            m1 = fminf(m1, fminf(b2f((unsigned short)(v0.x >> 16)), b2f((unsigned short)(v1.x >> 16))));
            m2 = fminf(m2, fminf(b2f((unsigned short)v0.y), b2f((unsigned short)v1.y)));
            m3 = fminf(m3, fminf(b2f((unsigned short)(v0.y >> 16)), b2f((unsigned short)(v1.y >> 16))));
        }
        if (i < b) {
            int s0 = (int)esrc[i];
            uint2 v0 = *(const uint2*)(Th + s0 * D + fb);
            m0 = fminf(m0, b2f((unsigned short)v0.x));
            m1 = fminf(m1, b2f((unsigned short)(v0.x >> 16)));
            m2 = fminf(m2, b2f((unsigned short)v0.y));
            m3 = fminf(m3, b2f((unsigned short)(v0.y >> 16)));
        }
    }
    // combine the 4 edge-groups: lanes l, l^16, l^32, l^48 share features
    m0 = fminf(m0, __shfl_xor(m0, 16, 64)); m0 = fminf(m0, __shfl_xor(m0, 32, 64));
    m1 = fminf(m1, __shfl_xor(m1, 16, 64)); m1 = fminf(m1, __shfl_xor(m1, 32, 64));
    m2 = fminf(m2, __shfl_xor(m2, 16, 64)); m2 = fminf(m2, __shfl_xor(m2, 32, 64));
    m3 = fminf(m3, __shfl_xor(m3, 16, 64)); m3 = fminf(m3, __shfl_xor(m3, 32, 64));
    if (lane < 16) {
        unsigned lo = (unsigned)f2b(m0) | ((unsigned)f2b(m1) << 16);
        unsigned hi = (unsigned)f2b(m2) | ((unsigned)f2b(m3) << 16);
        *(uint2*)(Mb + n * D + fb) = make_uint2(lo, hi);
    }
}

// ---------- kernel 6: out = feat@Wt + feat@Wp + bt + bp - min ----------
__global__ __launch_bounds__(256, 2)
void finalize(const void* __restrict__ featv,
              const void* __restrict__ Wtv, const void* __restrict__ btv,
              const void* __restrict__ Wpv, const void* __restrict__ bpv,
              const unsigned* __restrict__ flags,
              const unsigned short* __restrict__ Mb, void* __restrict__ outv) {
    const unsigned fp32mode = flags[0];
    const int lane = threadIdx.x & 63;
    const int wid  = threadIdx.x >> 6;

    float wt[D], wp[D], bsum;
    if (fp32mode) {
        const float* Wt = (const float*)Wtv;
        const float* Wp = (const float*)Wpv;
#pragma unroll
        for (int k = 0; k < D; ++k) { wt[k] = Wt[k * D + lane]; wp[k] = Wp[k * D + lane]; }
        bsum = ((const float*)btv)[lane] + ((const float*)bpv)[lane];
    } else {
        const unsigned short* Wt = (const unsigned short*)Wtv;
        const unsigned short* Wp = (const unsigned short*)Wpv;
#pragma unroll
        for (int k = 0; k < D; ++k) { wt[k] = b2f(Wt[k * D + lane]); wp[k] = b2f(Wp[k * D + lane]); }
        bsum = b2f(((const unsigned short*)btv)[lane]) + b2f(((const unsigned short*)bpv)[lane]);
    }

    const int nW = gridDim.x << 2;
    for (int r = (blockIdx.x << 2) + wid; r < N_NODES; r += nW) {
        float x = fp32mode ? ((const float*)featv)[r * D + lane]
                           : b2f(((const unsigned short*)featv)[r * D + lane]);
        float at = 0.f, ap = 0.f;
#pragma unroll
        for (int k = 0; k < D; ++k) {
            float f = __shfl(x, k, 64);
            at = fmaf(f, wt[k], at);
            ap = fmaf(f, wp[k], ap);
        }
        float res = at + ap + bsum - b2f(Mb[r * D + lane]);
        if (fp32mode) ((float*)outv)[r * D + lane] = res;
        else          ((unsigned short*)outv)[r * D + lane] = f2b(res);
    }
}

extern "C" void kernel_launch(void* const* d_in, const int* in_sizes, int n_in,
                              void* d_out, int out_size, void* d_ws, size_t ws_size,
                              hipStream_t stream) {
    // ws layout (~10.6 MB; known-safe budget <= 12.8 MB):
    char* p = (char*)d_ws;
    unsigned*       flags    = (unsigned*)p;                          // 256 B
    unsigned*       offsets  = (unsigned*)(p + 256);                  // 50016*4
    unsigned*       cnt4     = (unsigned*)(p + 256 + 200064);         // 4*50016*4 (counts -> cursors)
    unsigned*       esrc     = (unsigned*)(p + 256 + 200064 + 800256);            // 800000*4
    unsigned short* Mb       = (unsigned short*)(p + 256 + 200064 + 800256 + 3200000); // 6.4 MB
    unsigned*       partials = (unsigned*)(p + 256 + 200064 + 800256 + 3200000 + 6400000); // 1 KB

    detect_mode<<<1, 128, 0, stream>>>(d_in[0], d_in[1], flags);
    node_theta<<<1024, 256, 0, stream>>>(d_in[0], d_in[3], flags, d_out);
    hipMemsetAsync(cnt4, 0, (size_t)4 * NSLOT * sizeof(unsigned), stream);
    histogram<<<N_EDGES / 256, 256, 0, stream>>>(d_in[2], flags, cnt4);
    block_sums<<<NPART, 256, 0, stream>>>(cnt4, partials);
    scan_partials<<<1, 256, 0, stream>>>(partials);
    write_offsets<<<NPART, 256, 0, stream>>>(cnt4, partials, offsets);
    scatter_edges<<<N_EDGES / 256, 256, 0, stream>>>(d_in[1], d_in[2], flags, cnt4, esrc);
    min_gather<<<N_NODES / 4, 256, 0, stream>>>(offsets, esrc, d_out, flags, Mb);
    finalize<<<1024, 256, 0, stream>>>(d_in[0], d_in[3], d_in[4], d_in[5], d_in[6],
                                       flags, Mb, d_out);
}

// Round 6
// 224.400 us; speedup vs baseline: 1.9230x; 1.2269x over previous
//
#include <hip/hip_runtime.h>
#include <hip/hip_bf16.h>

#define N_NODES 50000
#define N_EDGES 800000
#define D 64
#define NB 196        // coarse buckets: dst>>8 -> 0..195
#define CHUNK_E 4096  // edges per partition block
#define NPB 196       // ceil(800000/4096)

// ---------- helpers ----------
__device__ __forceinline__ float b2f(unsigned short h) {
    return __uint_as_float(((unsigned)h) << 16);
}
__device__ __forceinline__ unsigned short f2b(float f) {
    __hip_bfloat16 t = __float2bfloat16(f);
    return *reinterpret_cast<unsigned short*>(&t);
}

// ---------- kernel 0: runtime dtype / index-width detection ----------
__global__ void detect_mode(const void* feat, const void* srcv, unsigned* flags) {
    const int t = threadIdx.x;          // 128 threads = 2 waves
    if (t < 64) {
        const unsigned short* p = (const unsigned short*)feat;
        float x = b2f(p[2 * t]);
        float a = fabsf(x);
        bool insane = !(a <= 64.f) || (x != 0.f && a < 9.3132e-10f);
        unsigned long long m = __ballot(insane);
        if (t == 0) flags[0] = (__popcll(m) >= 8) ? 1u : 0u;
    } else {
        const int* s32 = (const int*)srcv;
        int v = s32[2 * (t - 64) + 1];
        unsigned long long m = __ballot(v == 0);
        if (t == 64) flags[1] = (__popcll(m) >= 32) ? 1u : 0u;
    }
}

// ---------- kernel 1: T = feat @ W_theta -> d_out ----------
__global__ __launch_bounds__(256, 2)
void node_theta(const void* __restrict__ featv, const void* __restrict__ Wtv,
                const unsigned* __restrict__ flags, void* __restrict__ outv) {
    const unsigned fp32mode = flags[0];
    const int lane = threadIdx.x & 63;
    const int wid  = threadIdx.x >> 6;

    float wt[D];
    if (fp32mode) {
        const float* W = (const float*)Wtv;
#pragma unroll
        for (int k = 0; k < D; ++k) wt[k] = W[k * D + lane];
    } else {
        const unsigned short* W = (const unsigned short*)Wtv;
#pragma unroll
        for (int k = 0; k < D; ++k) wt[k] = b2f(W[k * D + lane]);
    }

    const int nW = gridDim.x << 2;
    for (int r = (blockIdx.x << 2) + wid; r < N_NODES; r += nW) {
        float x = fp32mode ? ((const float*)featv)[r * D + lane]
                           : b2f(((const unsigned short*)featv)[r * D + lane]);
        float at = 0.f;
#pragma unroll
        for (int k = 0; k < D; ++k)
            at = fmaf(__shfl(x, k, 64), wt[k], at);
        if (fp32mode) ((float*)outv)[r * D + lane] = at;
        else          ((unsigned short*)outv)[r * D + lane] = f2b(at);
    }
}

// ---------- kernel 2: coarse bucket counts (LDS-aggregated) ----------
__global__ __launch_bounds__(256)
void coarse_count(const void* __restrict__ dstv, const unsigned* __restrict__ flags,
                  unsigned* __restrict__ c_cnt) {
    __shared__ unsigned cnt[NB];
    const int t = threadIdx.x;
    if (t < NB) cnt[t] = 0;
    __syncthreads();
    const unsigned idx64 = flags[1];
    const int base = blockIdx.x * CHUNK_E;
#pragma unroll
    for (int j = 0; j < CHUNK_E / 256; ++j) {
        int e = base + j * 256 + t;
        if (e < N_EDGES) {
            int d = idx64 ? (int)((const long long*)dstv)[e] : ((const int*)dstv)[e];
            d = min(max(d, 0), N_NODES - 1);
            atomicAdd(&cnt[d >> 8], 1u);
        }
    }
    __syncthreads();
    if (t < NB && cnt[t]) atomicAdd(&c_cnt[t], cnt[t]);
}

// ---------- kernel 3: scan of NB coarse counts -> c_off, c_cur ----------
__global__ __launch_bounds__(256)
void scanNB(const unsigned* __restrict__ c_cnt, unsigned* __restrict__ c_off,
            unsigned* __restrict__ c_cur, unsigned* __restrict__ offsets) {
    __shared__ unsigned sm[256];
    const int t = threadIdx.x;
    unsigned v = (t < NB) ? c_cnt[t] : 0u;
    sm[t] = v;
    __syncthreads();
    for (int off = 1; off < 256; off <<= 1) {
        unsigned u = (t >= off) ? sm[t - off] : 0u;
        __syncthreads();
        sm[t] += u;
        __syncthreads();
    }
    if (t < NB) { c_off[t] = sm[t] - v; c_cur[t] = sm[t] - v; }
    if (t == 0) { c_off[NB] = N_EDGES; offsets[N_NODES] = N_EDGES; }
}

// ---------- kernel 4: coarse partition of packed (dst<<16|src) ----------
__global__ __launch_bounds__(256)
void coarse_scatter(const void* __restrict__ srcv, const void* __restrict__ dstv,
                    const unsigned* __restrict__ flags,
                    unsigned* __restrict__ c_cur, unsigned* __restrict__ packed) {
    __shared__ unsigned h[NB];
    const int t = threadIdx.x;
    if (t < NB) h[t] = 0;
    __syncthreads();
    const unsigned idx64 = flags[1];
    const int base = blockIdx.x * CHUNK_E;
    unsigned pk[CHUNK_E / 256];
#pragma unroll
    for (int j = 0; j < CHUNK_E / 256; ++j) {
        int e = base + j * 256 + t;
        unsigned p = 0xFFFFFFFFu;                      // sentinel (dst<=49999 < 0xFFFF)
        if (e < N_EDGES) {
            int s, d;
            if (idx64) {
                s = (int)((const long long*)srcv)[e];
                d = (int)((const long long*)dstv)[e];
            } else {
                s = ((const int*)srcv)[e];
                d = ((const int*)dstv)[e];
            }
            s = min(max(s, 0), N_NODES - 1);
            d = min(max(d, 0), N_NODES - 1);
            p = ((unsigned)d << 16) | (unsigned)s;
            atomicAdd(&h[d >> 8], 1u);
        }
        pk[j] = p;
    }
    __syncthreads();
    // one reservation atomic per (block,bucket); h becomes the LDS write cursor
    if (t < NB) h[t] = atomicAdd(&c_cur[t], h[t]);
    __syncthreads();
#pragma unroll
    for (int j = 0; j < CHUNK_E / 256; ++j) {
        unsigned p = pk[j];
        if (p != 0xFFFFFFFFu) {
            unsigned pos = atomicAdd(&h[p >> 24], 1u); // p>>24 == dst>>8
            packed[pos] = p;
        }
    }
}

// ---------- kernel 5: per-bucket node hist + scan + fine scatter (all LDS) ----------
__global__ __launch_bounds__(256)
void bucket_build(const unsigned* __restrict__ c_off, const unsigned* __restrict__ packed,
                  unsigned* __restrict__ offsets, unsigned short* __restrict__ esrc) {
    __shared__ unsigned h[256];   // node counts -> node cursors
    __shared__ unsigned s[256];   // scan buffer
    const int t = threadIdx.x;
    const int b = blockIdx.x;
    const int estart = (int)c_off[b];
    const int eend   = (int)c_off[b + 1];
    h[t] = 0;
    __syncthreads();
    for (int i = estart + t; i < eend; i += 256)
        atomicAdd(&h[(packed[i] >> 16) & 255], 1u);
    __syncthreads();
    unsigned c = h[t];
    s[t] = c;
    __syncthreads();
    for (int off = 1; off < 256; off <<= 1) {
        unsigned u = (t >= off) ? s[t - off] : 0u;
        __syncthreads();
        s[t] += u;
        __syncthreads();
    }
    unsigned pos0 = (unsigned)estart + s[t] - c;       // CSR start for this node
    h[t] = pos0;                                       // own slot only
    const int node = (b << 8) + t;
    if (node < N_NODES) offsets[node] = pos0;
    __syncthreads();
    for (int i = estart + t; i < eend; i += 256) {
        unsigned p = packed[i];
        unsigned pos = atomicAdd(&h[(p >> 16) & 255], 1u);
        esrc[pos] = (unsigned short)(p & 0xFFFFu);
    }
}

// ---------- kernel 6: vectorized per-node segmented min ----------
// lane = (edge-group g = lane>>4, feature-quad fb = (lane&15)*4)
__global__ __launch_bounds__(256)
void min_gather(const unsigned* __restrict__ offsets, const unsigned short* __restrict__ esrc,
                const void* __restrict__ outv /*T*/, const unsigned* __restrict__ flags,
                unsigned short* __restrict__ Mb) {
    const unsigned fp32mode = flags[0];
    const int lane = threadIdx.x & 63;
    const int wid  = threadIdx.x >> 6;
    const int n = (blockIdx.x << 2) + wid;             // grid exact: 12500*4 waves
    const int g  = lane >> 4;
    const int fb = (lane & 15) << 2;
    const int a = (int)offsets[n];
    const int b = (int)offsets[n + 1];
    const float FMAX = __uint_as_float(0x7f7fffffu);
    float m0 = FMAX, m1 = FMAX, m2 = FMAX, m3 = FMAX;

    int i = a + g;
    if (fp32mode) {
        const float* Tf = (const float*)outv;
        for (; i + 4 < b; i += 8) {                    // 2 gathers in flight
            int s0 = (int)esrc[i], s1 = (int)esrc[i + 4];
            float4 v0 = *(const float4*)(Tf + s0 * D + fb);
            float4 v1 = *(const float4*)(Tf + s1 * D + fb);
            m0 = fminf(m0, fminf(v0.x, v1.x));
            m1 = fminf(m1, fminf(v0.y, v1.y));
            m2 = fminf(m2, fminf(v0.z, v1.z));
            m3 = fminf(m3, fminf(v0.w, v1.w));
        }
        if (i < b) {
            int s0 = (int)esrc[i];
            float4 v0 = *(const float4*)(Tf + s0 * D + fb);
            m0 = fminf(m0, v0.x); m1 = fminf(m1, v0.y);
            m2 = fminf(m2, v0.z); m3 = fminf(m3, v0.w);
        }
    } else {
        const unsigned short* Th = (const unsigned short*)outv;
        for (; i + 4 < b; i += 8) {
            int s0 = (int)esrc[i], s1 = (int)esrc[i + 4];
            uint2 v0 = *(const uint2*)(Th + s0 * D + fb);
            uint2 v1 = *(const uint2*)(Th + s1 * D + fb);
            m0 = fminf(m0, fminf(b2f((unsigned short)v0.x), b2f((unsigned short)v1.x)));
            m1 = fminf(m1, fminf(b2f((unsigned short)(v0.x >> 16)), b2f((unsigned short)(v1.x >> 16))));
            m2 = fminf(m2, fminf(b2f((unsigned short)v0.y), b2f((unsigned short)v1.y)));
            m3 = fminf(m3, fminf(b2f((unsigned short)(v0.y >> 16)), b2f((unsigned short)(v1.y >> 16))));
        }
        if (i < b) {
            int s0 = (int)esrc[i];
            uint2 v0 = *(const uint2*)(Th + s0 * D + fb);
            m0 = fminf(m0, b2f((unsigned short)v0.x));
            m1 = fminf(m1, b2f((unsigned short)(v0.x >> 16)));
            m2 = fminf(m2, b2f((unsigned short)v0.y));
            m3 = fminf(m3, b2f((unsigned short)(v0.y >> 16)));
        }
    }
    // combine the 4 edge-groups: lanes l, l^16, l^32, l^48 share features
    m0 = fminf(m0, __shfl_xor(m0, 16, 64)); m0 = fminf(m0, __shfl_xor(m0, 32, 64));
    m1 = fminf(m1, __shfl_xor(m1, 16, 64)); m1 = fminf(m1, __shfl_xor(m1, 32, 64));
    m2 = fminf(m2, __shfl_xor(m2, 16, 64)); m2 = fminf(m2, __shfl_xor(m2, 32, 64));
    m3 = fminf(m3, __shfl_xor(m3, 16, 64)); m3 = fminf(m3, __shfl_xor(m3, 32, 64));
    if (lane < 16) {
        unsigned lo = (unsigned)f2b(m0) | ((unsigned)f2b(m1) << 16);
        unsigned hi = (unsigned)f2b(m2) | ((unsigned)f2b(m3) << 16);
        *(uint2*)(Mb + n * D + fb) = make_uint2(lo, hi);
    }
}

// ---------- kernel 7: out = feat@Wt + feat@Wp + bt + bp - min ----------
__global__ __launch_bounds__(256, 2)
void finalize(const void* __restrict__ featv,
              const void* __restrict__ Wtv, const void* __restrict__ btv,
              const void* __restrict__ Wpv, const void* __restrict__ bpv,
              const unsigned* __restrict__ flags,
              const unsigned short* __restrict__ Mb, void* __restrict__ outv) {
    const unsigned fp32mode = flags[0];
    const int lane = threadIdx.x & 63;
    const int wid  = threadIdx.x >> 6;

    float wt[D], wp[D], bsum;
    if (fp32mode) {
        const float* Wt = (const float*)Wtv;
        const float* Wp = (const float*)Wpv;
#pragma unroll
        for (int k = 0; k < D; ++k) { wt[k] = Wt[k * D + lane]; wp[k] = Wp[k * D + lane]; }
        bsum = ((const float*)btv)[lane] + ((const float*)bpv)[lane];
    } else {
        const unsigned short* Wt = (const unsigned short*)Wtv;
        const unsigned short* Wp = (const unsigned short*)Wpv;
#pragma unroll
        for (int k = 0; k < D; ++k) { wt[k] = b2f(Wt[k * D + lane]); wp[k] = b2f(Wp[k * D + lane]); }
        bsum = b2f(((const unsigned short*)btv)[lane]) + b2f(((const unsigned short*)bpv)[lane]);
    }

    const int nW = gridDim.x << 2;
    for (int r = (blockIdx.x << 2) + wid; r < N_NODES; r += nW) {
        float x = fp32mode ? ((const float*)featv)[r * D + lane]
                           : b2f(((const unsigned short*)featv)[r * D + lane]);
        float at = 0.f, ap = 0.f;
#pragma unroll
        for (int k = 0; k < D; ++k) {
            float f = __shfl(x, k, 64);
            at = fmaf(f, wt[k], at);
            ap = fmaf(f, wp[k], ap);
        }
        float res = at + ap + bsum - b2f(Mb[r * D + lane]);
        if (fp32mode) ((float*)outv)[r * D + lane] = res;
        else          ((unsigned short*)outv)[r * D + lane] = f2b(res);
    }
}

extern "C" void kernel_launch(void* const* d_in, const int* in_sizes, int n_in,
                              void* d_out, int out_size, void* d_ws, size_t ws_size,
                              hipStream_t stream) {
    // ws layout (~11.4 MB; known-safe budget <= 12.8 MB):
    char* p = (char*)d_ws;
    unsigned*       flags   = (unsigned*)p;                      // 256 B
    unsigned*       offsets = (unsigned*)(p + 256);              // 50017*4 -> pad 200320
    unsigned*       c_cnt   = (unsigned*)(p + 256 + 200320);     // 196*4 -> 1024
    unsigned*       c_off   = (unsigned*)(p + 256 + 201344);     // 197*4 -> 1024
    unsigned*       c_cur   = (unsigned*)(p + 256 + 202368);     // 196*4 -> 1024
    unsigned*       packed  = (unsigned*)(p + 256 + 203392);     // 800000*4 = 3.2 MB
    unsigned short* esrc    = (unsigned short*)(p + 256 + 203392 + 3200000);  // 1.6 MB
    unsigned short* Mb      = (unsigned short*)(p + 256 + 203392 + 3200000 + 1600000); // 6.4 MB

    detect_mode<<<1, 128, 0, stream>>>(d_in[0], d_in[1], flags);
    node_theta<<<1024, 256, 0, stream>>>(d_in[0], d_in[3], flags, d_out);
    hipMemsetAsync(c_cnt, 0, NB * sizeof(unsigned), stream);
    coarse_count<<<NPB, 256, 0, stream>>>(d_in[2], flags, c_cnt);
    scanNB<<<1, 256, 0, stream>>>(c_cnt, c_off, c_cur, offsets);
    coarse_scatter<<<NPB, 256, 0, stream>>>(d_in[1], d_in[2], flags, c_cur, packed);
    bucket_build<<<NB, 256, 0, stream>>>(c_off, packed, offsets, esrc);
    min_gather<<<N_NODES / 4, 256, 0, stream>>>(offsets, esrc, d_out, flags, Mb);
    finalize<<<1024, 256, 0, stream>>>(d_in[0], d_in[3], d_in[4], d_in[5], d_in[6],
                                       flags, Mb, d_out);
}

// Round 7
// 209.605 us; speedup vs baseline: 2.0587x; 1.0706x over previous
//
#include <hip/hip_runtime.h>
#include <hip/hip_bf16.h>

#define N_NODES 50000
#define N_EDGES 800000
#define D 64
#define NB 196        // coarse buckets: dst>>8 -> 0..195
#define CHUNK_E 4096  // edges per partition block
#define NPB 196       // ceil(800000/4096)

typedef __attribute__((ext_vector_type(8))) short short8v;   // 8 bf16 (4 VGPRs)
typedef __attribute__((ext_vector_type(4))) float float4v;   // 4 fp32 acc

// ---------- helpers ----------
__device__ __forceinline__ float b2f(unsigned short h) {
    return __uint_as_float(((unsigned)h) << 16);
}
__device__ __forceinline__ unsigned short f2b(float f) {
    __hip_bfloat16 t = __float2bfloat16(f);
    return *reinterpret_cast<unsigned short*>(&t);
}

// ---------- kernel 0: runtime dtype / index-width detection ----------
__global__ void detect_mode(const void* feat, const void* srcv, unsigned* flags) {
    const int t = threadIdx.x;          // 128 threads = 2 waves
    if (t < 64) {
        const unsigned short* p = (const unsigned short*)feat;
        float x = b2f(p[2 * t]);
        float a = fabsf(x);
        bool insane = !(a <= 64.f) || (x != 0.f && a < 9.3132e-10f);
        unsigned long long m = __ballot(insane);
        if (t == 0) flags[0] = (__popcll(m) >= 8) ? 1u : 0u;
    } else {
        const int* s32 = (const int*)srcv;
        int v = s32[2 * (t - 64) + 1];
        unsigned long long m = __ballot(v == 0);
        if (t == 64) flags[1] = (__popcll(m) >= 32) ? 1u : 0u;
    }
}

// ---------- kernel 1: MFMA node transforms ----------
// T = feat@Wt -> T16 (ws) ; C = feat@(Wt) + feat@Wp + bt + bp -> d_out
__global__ __launch_bounds__(256)
void node_both(const void* __restrict__ featv,
               const void* __restrict__ Wtv, const void* __restrict__ btv,
               const void* __restrict__ Wpv, const void* __restrict__ bpv,
               const unsigned* __restrict__ flags,
               unsigned short* __restrict__ T16, void* __restrict__ outv) {
    const int lane = threadIdx.x & 63;
    const int wid  = threadIdx.x >> 6;
    const int w = blockIdx.x * 4 + wid;                // wave id

    if (flags[0] == 0) {
        // ---- bf16 MFMA path: one 16-row strip per wave ----
        if (w >= N_NODES / 16) return;                 // 3125 strips exact
        const short* F  = (const short*)featv;
        const short* Wt = (const short*)Wtv;
        const short* Wp = (const short*)Wpv;
        const unsigned short* bt = (const unsigned short*)btv;
        const unsigned short* bp = (const unsigned short*)bpv;
        const int m = lane & 15, q = lane >> 4;

        // A frags: A[m=lane&15][k=q*8+j] ; two k-halves
        const short* fr = F + (w * 16 + m) * D + q * 8;
        short8v A0 = *(const short8v*)fr;
        short8v A1 = *(const short8v*)(fr + 32);

        float4v accT[4], accP[4];
#pragma unroll
        for (int c = 0; c < 4; ++c) {
            short8v Bt0, Bt1, Bp0, Bp1;
            const int col = 16 * c + m;
#pragma unroll
            for (int j = 0; j < 8; ++j) {              // B[k=q*8+j][n=col]
                Bt0[j] = Wt[(q * 8 + j) * D + col];
                Bt1[j] = Wt[(32 + q * 8 + j) * D + col];
                Bp0[j] = Wp[(q * 8 + j) * D + col];
                Bp1[j] = Wp[(32 + q * 8 + j) * D + col];
            }
            float bs = b2f(bt[col]) + b2f(bp[col]);
            accT[c] = (float4v){0.f, 0.f, 0.f, 0.f};
            accP[c] = (float4v){bs, bs, bs, bs};
            accT[c] = __builtin_amdgcn_mfma_f32_16x16x32_bf16(A0, Bt0, accT[c], 0, 0, 0);
            accT[c] = __builtin_amdgcn_mfma_f32_16x16x32_bf16(A1, Bt1, accT[c], 0, 0, 0);
            accP[c] = __builtin_amdgcn_mfma_f32_16x16x32_bf16(A0, Bp0, accP[c], 0, 0, 0);
            accP[c] = __builtin_amdgcn_mfma_f32_16x16x32_bf16(A1, Bp1, accP[c], 0, 0, 0);
        }
        // C/D layout: col = lane&15 (+16c), row = q*4 + reg
        unsigned short* Cout = (unsigned short*)outv;
#pragma unroll
        for (int c = 0; c < 4; ++c) {
            const int col = 16 * c + m;
#pragma unroll
            for (int r = 0; r < 4; ++r) {
                const int row = w * 16 + q * 4 + r;
                T16[row * D + col]  = f2b(accT[c][r]);
                Cout[row * D + col] = f2b(accT[c][r] + accP[c][r]);
            }
        }
    } else {
        // ---- fp32 fallback: shuffle GEMM (T stored bf16 best-effort) ----
        const float* F  = (const float*)featv;
        const float* Wt = (const float*)Wtv;
        const float* Wp = (const float*)Wpv;
        float wt[D], wp[D];
#pragma unroll
        for (int k = 0; k < D; ++k) { wt[k] = Wt[k * D + lane]; wp[k] = Wp[k * D + lane]; }
        const float bsum = ((const float*)btv)[lane] + ((const float*)bpv)[lane];
        float* Cout = (float*)outv;
        for (int r = w * 16; r < min(w * 16 + 16, N_NODES); ++r) {
            float x = F[r * D + lane];
            float at = 0.f, ap = 0.f;
#pragma unroll
            for (int k = 0; k < D; ++k) {
                float f = __shfl(x, k, 64);
                at = fmaf(f, wt[k], at);
                ap = fmaf(f, wp[k], ap);
            }
            T16[r * D + lane]  = f2b(at);
            Cout[r * D + lane] = at + ap + bsum;
        }
    }
}

// ---------- kernel 2: coarse bucket counts (LDS-aggregated) ----------
__global__ __launch_bounds__(256)
void coarse_count(const void* __restrict__ dstv, const unsigned* __restrict__ flags,
                  unsigned* __restrict__ c_cnt) {
    __shared__ unsigned cnt[NB];
    const int t = threadIdx.x;
    if (t < NB) cnt[t] = 0;
    __syncthreads();
    const unsigned idx64 = flags[1];
    const int base = blockIdx.x * CHUNK_E;
#pragma unroll
    for (int j = 0; j < CHUNK_E / 256; ++j) {
        int e = base + j * 256 + t;
        if (e < N_EDGES) {
            int d = idx64 ? (int)((const long long*)dstv)[e] : ((const int*)dstv)[e];
            d = min(max(d, 0), N_NODES - 1);
            atomicAdd(&cnt[d >> 8], 1u);
        }
    }
    __syncthreads();
    if (t < NB && cnt[t]) atomicAdd(&c_cnt[t], cnt[t]);
}

// ---------- kernel 3: scan of NB coarse counts -> c_off, c_cur ----------
__global__ __launch_bounds__(256)
void scanNB(const unsigned* __restrict__ c_cnt, unsigned* __restrict__ c_off,
            unsigned* __restrict__ c_cur, unsigned* __restrict__ offsets) {
    __shared__ unsigned sm[256];
    const int t = threadIdx.x;
    unsigned v = (t < NB) ? c_cnt[t] : 0u;
    sm[t] = v;
    __syncthreads();
    for (int off = 1; off < 256; off <<= 1) {
        unsigned u = (t >= off) ? sm[t - off] : 0u;
        __syncthreads();
        sm[t] += u;
        __syncthreads();
    }
    if (t < NB) { c_off[t] = sm[t] - v; c_cur[t] = sm[t] - v; }
    if (t == 0) { c_off[NB] = N_EDGES; offsets[N_NODES] = N_EDGES; }
}

// ---------- kernel 4: coarse partition of packed (dst<<16|src) ----------
__global__ __launch_bounds__(256)
void coarse_scatter(const void* __restrict__ srcv, const void* __restrict__ dstv,
                    const unsigned* __restrict__ flags,
                    unsigned* __restrict__ c_cur, unsigned* __restrict__ packed) {
    __shared__ unsigned h[NB];
    const int t = threadIdx.x;
    if (t < NB) h[t] = 0;
    __syncthreads();
    const unsigned idx64 = flags[1];
    const int base = blockIdx.x * CHUNK_E;
    unsigned pk[CHUNK_E / 256];
#pragma unroll
    for (int j = 0; j < CHUNK_E / 256; ++j) {
        int e = base + j * 256 + t;
        unsigned p = 0xFFFFFFFFu;                      // sentinel (dst<=49999 < 0xFFFF)
        if (e < N_EDGES) {
            int s, d;
            if (idx64) {
                s = (int)((const long long*)srcv)[e];
                d = (int)((const long long*)dstv)[e];
            } else {
                s = ((const int*)srcv)[e];
                d = ((const int*)dstv)[e];
            }
            s = min(max(s, 0), N_NODES - 1);
            d = min(max(d, 0), N_NODES - 1);
            p = ((unsigned)d << 16) | (unsigned)s;
            atomicAdd(&h[d >> 8], 1u);
        }
        pk[j] = p;
    }
    __syncthreads();
    // one reservation atomic per (block,bucket); h becomes the LDS write cursor
    if (t < NB) h[t] = atomicAdd(&c_cur[t], h[t]);
    __syncthreads();
#pragma unroll
    for (int j = 0; j < CHUNK_E / 256; ++j) {
        unsigned p = pk[j];
        if (p != 0xFFFFFFFFu) {
            unsigned pos = atomicAdd(&h[p >> 24], 1u); // p>>24 == dst>>8
            packed[pos] = p;
        }
    }
}

// ---------- kernel 5: per-bucket node hist + scan + fine scatter (all LDS) ----------
__global__ __launch_bounds__(256)
void bucket_build(const unsigned* __restrict__ c_off, const unsigned* __restrict__ packed,
                  unsigned* __restrict__ offsets, unsigned short* __restrict__ esrc) {
    __shared__ unsigned h[256];   // node counts -> node cursors
    __shared__ unsigned s[256];   // scan buffer
    const int t = threadIdx.x;
    const int b = blockIdx.x;
    const int estart = (int)c_off[b];
    const int eend   = (int)c_off[b + 1];
    h[t] = 0;
    __syncthreads();
    for (int i = estart + t; i < eend; i += 256)
        atomicAdd(&h[(packed[i] >> 16) & 255], 1u);
    __syncthreads();
    unsigned c = h[t];
    s[t] = c;
    __syncthreads();
    for (int off = 1; off < 256; off <<= 1) {
        unsigned u = (t >= off) ? s[t - off] : 0u;
        __syncthreads();
        s[t] += u;
        __syncthreads();
    }
    unsigned pos0 = (unsigned)estart + s[t] - c;       // CSR start for this node
    h[t] = pos0;                                       // own slot only
    const int node = (b << 8) + t;
    if (node < N_NODES) offsets[node] = pos0;
    __syncthreads();
    for (int i = estart + t; i < eend; i += 256) {
        unsigned p = packed[i];
        unsigned pos = atomicAdd(&h[(p >> 16) & 255], 1u);
        esrc[pos] = (unsigned short)(p & 0xFFFFu);
    }
}

// ---------- kernel 6: per-node segmented min + fused epilogue ----------
// lane = (edge-group g = lane>>4, feature-quad fb = (lane&15)*4)
// out[n] = C[n] - min ; C read from d_out, overwritten in place (own row only)
__global__ __launch_bounds__(256)
void min_gather(const unsigned* __restrict__ offsets, const unsigned short* __restrict__ esrc,
                const unsigned short* __restrict__ T16, const unsigned* __restrict__ flags,
                void* __restrict__ outv) {
    const unsigned fp32mode = flags[0];
    const int lane = threadIdx.x & 63;
    const int wid  = threadIdx.x >> 6;
    const int n = (blockIdx.x << 2) + wid;             // grid exact: 12500*4 waves
    const int g  = lane >> 4;
    const int fb = (lane & 15) << 2;
    const int a = (int)offsets[n];
    const int b = (int)offsets[n + 1];
    const float FMAX = __uint_as_float(0x7f7fffffu);
    float m0 = FMAX, m1 = FMAX, m2 = FMAX, m3 = FMAX;

    int i = a + g;
    for (; i + 4 < b; i += 8) {                        // 2 gathers in flight
        int s0 = (int)esrc[i], s1 = (int)esrc[i + 4];
        uint2 v0 = *(const uint2*)(T16 + s0 * D + fb);
        uint2 v1 = *(const uint2*)(T16 + s1 * D + fb);
        m0 = fminf(m0, fminf(b2f((unsigned short)v0.x), b2f((unsigned short)v1.x)));
        m1 = fminf(m1, fminf(b2f((unsigned short)(v0.x >> 16)), b2f((unsigned short)(v1.x >> 16))));
        m2 = fminf(m2, fminf(b2f((unsigned short)v0.y), b2f((unsigned short)v1.y)));
        m3 = fminf(m3, fminf(b2f((unsigned short)(v0.y >> 16)), b2f((unsigned short)(v1.y >> 16))));
    }
    if (i < b) {
        int s0 = (int)esrc[i];
        uint2 v0 = *(const uint2*)(T16 + s0 * D + fb);
        m0 = fminf(m0, b2f((unsigned short)v0.x));
        m1 = fminf(m1, b2f((unsigned short)(v0.x >> 16)));
        m2 = fminf(m2, b2f((unsigned short)v0.y));
        m3 = fminf(m3, b2f((unsigned short)(v0.y >> 16)));
    }
    // combine the 4 edge-groups: lanes l, l^16, l^32, l^48 share features
    m0 = fminf(m0, __shfl_xor(m0, 16, 64)); m0 = fminf(m0, __shfl_xor(m0, 32, 64));
    m1 = fminf(m1, __shfl_xor(m1, 16, 64)); m1 = fminf(m1, __shfl_xor(m1, 32, 64));
    m2 = fminf(m2, __shfl_xor(m2, 16, 64)); m2 = fminf(m2, __shfl_xor(m2, 32, 64));
    m3 = fminf(m3, __shfl_xor(m3, 16, 64)); m3 = fminf(m3, __shfl_xor(m3, 32, 64));
    if (lane < 16) {
        if (fp32mode) {
            float* C = (float*)outv + n * D + fb;
            float4 c = *(const float4*)C;
            *(float4*)C = make_float4(c.x - m0, c.y - m1, c.z - m2, c.w - m3);
        } else {
            unsigned short* C = (unsigned short*)outv + n * D + fb;
            uint2 c = *(const uint2*)C;
            unsigned lo = (unsigned)f2b(b2f((unsigned short)c.x) - m0)
                        | ((unsigned)f2b(b2f((unsigned short)(c.x >> 16)) - m1) << 16);
            unsigned hi = (unsigned)f2b(b2f((unsigned short)c.y) - m2)
                        | ((unsigned)f2b(b2f((unsigned short)(c.y >> 16)) - m3) << 16);
            *(uint2*)C = make_uint2(lo, hi);
        }
    }
}

extern "C" void kernel_launch(void* const* d_in, const int* in_sizes, int n_in,
                              void* d_out, int out_size, void* d_ws, size_t ws_size,
                              hipStream_t stream) {
    // ws layout (~11.4 MB; known-safe budget <= 12.8 MB):
    char* p = (char*)d_ws;
    unsigned*       flags   = (unsigned*)p;                      // 256 B
    unsigned*       offsets = (unsigned*)(p + 256);              // 50017*4 -> pad 200320
    unsigned*       c_cnt   = (unsigned*)(p + 256 + 200320);     // 1024
    unsigned*       c_off   = (unsigned*)(p + 256 + 201344);     // 1024
    unsigned*       c_cur   = (unsigned*)(p + 256 + 202368);     // 1024
    unsigned*       packed  = (unsigned*)(p + 256 + 203392);     // 3.2 MB
    unsigned short* esrc    = (unsigned short*)(p + 256 + 203392 + 3200000);  // 1.6 MB
    unsigned short* T16     = (unsigned short*)(p + 256 + 203392 + 3200000 + 1600000); // 6.4 MB

    detect_mode<<<1, 128, 0, stream>>>(d_in[0], d_in[1], flags);
    node_both<<<(N_NODES / 16 + 3) / 4, 256, 0, stream>>>(d_in[0], d_in[3], d_in[4],
                                                          d_in[5], d_in[6], flags, T16, d_out);
    hipMemsetAsync(c_cnt, 0, NB * sizeof(unsigned), stream);
    coarse_count<<<NPB, 256, 0, stream>>>(d_in[2], flags, c_cnt);
    scanNB<<<1, 256, 0, stream>>>(c_cnt, c_off, c_cur, offsets);
    coarse_scatter<<<NPB, 256, 0, stream>>>(d_in[1], d_in[2], flags, c_cur, packed);
    bucket_build<<<NB, 256, 0, stream>>>(c_off, packed, offsets, esrc);
    min_gather<<<N_NODES / 4, 256, 0, stream>>>(offsets, esrc, T16, flags, d_out);
}

// Round 8
// 206.853 us; speedup vs baseline: 2.0861x; 1.0133x over previous
//
#include <hip/hip_runtime.h>
#include <hip/hip_bf16.h>

#define N_NODES 50000
#define N_EDGES 800000
#define D 64
#define NB 196        // coarse buckets: dst>>8 -> 0..195
#define CHUNK_E 4096  // edges per partition block
#define NPB 196       // ceil(800000/4096)

typedef __attribute__((ext_vector_type(8))) short short8v;   // 8 bf16 (4 VGPRs)
typedef __attribute__((ext_vector_type(4))) float float4v;   // 4 fp32 acc

// ---------- helpers ----------
__device__ __forceinline__ float b2f(unsigned short h) {
    return __uint_as_float(((unsigned)h) << 16);
}
__device__ __forceinline__ unsigned short f2b(float f) {
    __hip_bfloat16 t = __float2bfloat16(f);
    return *reinterpret_cast<unsigned short*>(&t);
}

// ---------- kernel 0: runtime dtype / index-width detection ----------
__global__ void detect_mode(const void* feat, const void* srcv, unsigned* flags) {
    const int t = threadIdx.x;          // 128 threads = 2 waves
    if (t < 64) {
        const unsigned short* p = (const unsigned short*)feat;
        float x = b2f(p[2 * t]);
        float a = fabsf(x);
        bool insane = !(a <= 64.f) || (x != 0.f && a < 9.3132e-10f);
        unsigned long long m = __ballot(insane);
        if (t == 0) flags[0] = (__popcll(m) >= 8) ? 1u : 0u;
    } else {
        const int* s32 = (const int*)srcv;
        int v = s32[2 * (t - 64) + 1];
        unsigned long long m = __ballot(v == 0);
        if (t == 64) flags[1] = (__popcll(m) >= 32) ? 1u : 0u;
    }
}

// ---------- kernel 1: MFMA node transforms (B frags hoisted, grid-stride strips) ----------
// T = feat@Wt -> T16 (ws) ; C = feat@Wt + feat@Wp + bt + bp -> d_out
__global__ __launch_bounds__(256)
void node_both(const void* __restrict__ featv,
               const void* __restrict__ Wtv, const void* __restrict__ btv,
               const void* __restrict__ Wpv, const void* __restrict__ bpv,
               const unsigned* __restrict__ flags,
               unsigned short* __restrict__ T16, void* __restrict__ outv) {
    const int lane = threadIdx.x & 63;
    const int wid  = threadIdx.x >> 6;
    const int wstart = blockIdx.x * 4 + wid;
    const int nwaves = gridDim.x * 4;

    if (flags[0] == 0) {
        // ---- bf16 MFMA path ----
        const short* F  = (const short*)featv;
        const short* Wt = (const short*)Wtv;
        const short* Wp = (const short*)Wpv;
        const unsigned short* bt = (const unsigned short*)btv;
        const unsigned short* bp = (const unsigned short*)bpv;
        const int m = lane & 15, q = lane >> 4;

        // B fragments: built ONCE per wave (W is 16 KB, L1/L2-hot), reused
        // across ~3 strips. Round-7 rebuilt these per strip -> 85us.
        short8v Bt0[4], Bt1[4], Bp0[4], Bp1[4];
        float bsv[4];
#pragma unroll
        for (int c = 0; c < 4; ++c) {
            const int col = 16 * c + m;
#pragma unroll
            for (int j = 0; j < 8; ++j) {              // B[k=q*8+j][n=col]
                Bt0[c][j] = Wt[(q * 8 + j) * D + col];
                Bt1[c][j] = Wt[(32 + q * 8 + j) * D + col];
                Bp0[c][j] = Wp[(q * 8 + j) * D + col];
                Bp1[c][j] = Wp[(32 + q * 8 + j) * D + col];
            }
            bsv[c] = b2f(bt[col]) + b2f(bp[col]);
        }

        unsigned short* Cout = (unsigned short*)outv;
        for (int w = wstart; w < N_NODES / 16; w += nwaves) {
            // A frags: A[m=lane&15][k=q*8+j] ; two k-halves
            const short* fr = F + (w * 16 + m) * D + q * 8;
            short8v A0 = *(const short8v*)fr;
            short8v A1 = *(const short8v*)(fr + 32);

#pragma unroll
            for (int c = 0; c < 4; ++c) {
                float4v accT = (float4v){0.f, 0.f, 0.f, 0.f};
                float4v accP = (float4v){bsv[c], bsv[c], bsv[c], bsv[c]};
                accT = __builtin_amdgcn_mfma_f32_16x16x32_bf16(A0, Bt0[c], accT, 0, 0, 0);
                accT = __builtin_amdgcn_mfma_f32_16x16x32_bf16(A1, Bt1[c], accT, 0, 0, 0);
                accP = __builtin_amdgcn_mfma_f32_16x16x32_bf16(A0, Bp0[c], accP, 0, 0, 0);
                accP = __builtin_amdgcn_mfma_f32_16x16x32_bf16(A1, Bp1[c], accP, 0, 0, 0);
                // C/D layout: col = lane&15 (+16c), row = q*4 + reg
                const int col = 16 * c + m;
#pragma unroll
                for (int r = 0; r < 4; ++r) {
                    const int row = w * 16 + q * 4 + r;
                    T16[row * D + col]  = f2b(accT[r]);
                    Cout[row * D + col] = f2b(accT[r] + accP[r]);
                }
            }
        }
    } else {
        // ---- fp32 fallback: shuffle GEMM (T stored bf16 best-effort) ----
        const float* F  = (const float*)featv;
        const float* Wt = (const float*)Wtv;
        const float* Wp = (const float*)Wpv;
        float wt[D], wp[D];
#pragma unroll
        for (int k = 0; k < D; ++k) { wt[k] = Wt[k * D + lane]; wp[k] = Wp[k * D + lane]; }
        const float bsum = ((const float*)btv)[lane] + ((const float*)bpv)[lane];
        float* Cout = (float*)outv;
        for (int w = wstart; w < N_NODES / 16 + 1; w += nwaves) {
            for (int r = w * 16; r < min(w * 16 + 16, N_NODES); ++r) {
                float x = F[r * D + lane];
                float at = 0.f, ap = 0.f;
#pragma unroll
                for (int k = 0; k < D; ++k) {
                    float f = __shfl(x, k, 64);
                    at = fmaf(f, wt[k], at);
                    ap = fmaf(f, wp[k], ap);
                }
                T16[r * D + lane]  = f2b(at);
                Cout[r * D + lane] = at + ap + bsum;
            }
        }
    }
}

// ---------- kernel 2: coarse bucket counts (LDS-aggregated) ----------
__global__ __launch_bounds__(256)
void coarse_count(const void* __restrict__ dstv, const unsigned* __restrict__ flags,
                  unsigned* __restrict__ c_cnt) {
    __shared__ unsigned cnt[NB];
    const int t = threadIdx.x;
    if (t < NB) cnt[t] = 0;
    __syncthreads();
    const unsigned idx64 = flags[1];
    const int base = blockIdx.x * CHUNK_E;
#pragma unroll
    for (int j = 0; j < CHUNK_E / 256; ++j) {
        int e = base + j * 256 + t;
        if (e < N_EDGES) {
            int d = idx64 ? (int)((const long long*)dstv)[e] : ((const int*)dstv)[e];
            d = min(max(d, 0), N_NODES - 1);
            atomicAdd(&cnt[d >> 8], 1u);
        }
    }
    __syncthreads();
    if (t < NB && cnt[t]) atomicAdd(&c_cnt[t], cnt[t]);
}

// ---------- kernel 3: scan of NB coarse counts -> c_off, c_cur ----------
__global__ __launch_bounds__(256)
void scanNB(const unsigned* __restrict__ c_cnt, unsigned* __restrict__ c_off,
            unsigned* __restrict__ c_cur, unsigned* __restrict__ offsets) {
    __shared__ unsigned sm[256];
    const int t = threadIdx.x;
    unsigned v = (t < NB) ? c_cnt[t] : 0u;
    sm[t] = v;
    __syncthreads();
    for (int off = 1; off < 256; off <<= 1) {
        unsigned u = (t >= off) ? sm[t - off] : 0u;
        __syncthreads();
        sm[t] += u;
        __syncthreads();
    }
    if (t < NB) { c_off[t] = sm[t] - v; c_cur[t] = sm[t] - v; }
    if (t == 0) { c_off[NB] = N_EDGES; offsets[N_NODES] = N_EDGES; }
}

// ---------- kernel 4: coarse partition of packed (dst<<16|src) ----------
__global__ __launch_bounds__(256)
void coarse_scatter(const void* __restrict__ srcv, const void* __restrict__ dstv,
                    const unsigned* __restrict__ flags,
                    unsigned* __restrict__ c_cur, unsigned* __restrict__ packed) {
    __shared__ unsigned h[NB];
    const int t = threadIdx.x;
    if (t < NB) h[t] = 0;
    __syncthreads();
    const unsigned idx64 = flags[1];
    const int base = blockIdx.x * CHUNK_E;
    unsigned pk[CHUNK_E / 256];
#pragma unroll
    for (int j = 0; j < CHUNK_E / 256; ++j) {
        int e = base + j * 256 + t;
        unsigned p = 0xFFFFFFFFu;                      // sentinel (dst<=49999 < 0xFFFF)
        if (e < N_EDGES) {
            int s, d;
            if (idx64) {
                s = (int)((const long long*)srcv)[e];
                d = (int)((const long long*)dstv)[e];
            } else {
                s = ((const int*)srcv)[e];
                d = ((const int*)dstv)[e];
            }
            s = min(max(s, 0), N_NODES - 1);
            d = min(max(d, 0), N_NODES - 1);
            p = ((unsigned)d << 16) | (unsigned)s;
            atomicAdd(&h[d >> 8], 1u);
        }
        pk[j] = p;
    }
    __syncthreads();
    // one reservation atomic per (block,bucket); h becomes the LDS write cursor
    if (t < NB) h[t] = atomicAdd(&c_cur[t], h[t]);
    __syncthreads();
#pragma unroll
    for (int j = 0; j < CHUNK_E / 256; ++j) {
        unsigned p = pk[j];
        if (p != 0xFFFFFFFFu) {
            unsigned pos = atomicAdd(&h[p >> 24], 1u); // p>>24 == dst>>8
            packed[pos] = p;
        }
    }
}

// ---------- kernel 5: per-bucket node hist + scan + fine scatter (all LDS) ----------
__global__ __launch_bounds__(256)
void bucket_build(const unsigned* __restrict__ c_off, const unsigned* __restrict__ packed,
                  unsigned* __restrict__ offsets, unsigned short* __restrict__ esrc) {
    __shared__ unsigned h[256];   // node counts -> node cursors
    __shared__ unsigned s[256];   // scan buffer
    const int t = threadIdx.x;
    const int b = blockIdx.x;
    const int estart = (int)c_off[b];
    const int eend   = (int)c_off[b + 1];
    h[t] = 0;
    __syncthreads();
    for (int i = estart + t; i < eend; i += 256)
        atomicAdd(&h[(packed[i] >> 16) & 255], 1u);
    __syncthreads();
    unsigned c = h[t];
    s[t] = c;
    __syncthreads();
    for (int off = 1; off < 256; off <<= 1) {
        unsigned u = (t >= off) ? s[t - off] : 0u;
        __syncthreads();
        s[t] += u;
        __syncthreads();
    }
    unsigned pos0 = (unsigned)estart + s[t] - c;       // CSR start for this node
    h[t] = pos0;                                       // own slot only
    const int node = (b << 8) + t;
    if (node < N_NODES) offsets[node] = pos0;
    __syncthreads();
    for (int i = estart + t; i < eend; i += 256) {
        unsigned p = packed[i];
        unsigned pos = atomicAdd(&h[(p >> 16) & 255], 1u);
        esrc[pos] = (unsigned short)(p & 0xFFFFu);
    }
}

// ---------- kernel 6: per-node segmented min + fused epilogue ----------
// lane = (edge-group g = lane>>4, feature-quad fb = (lane&15)*4)
// out[n] = C[n] - min ; C read from d_out, overwritten in place (own row only)
__global__ __launch_bounds__(256)
void min_gather(const unsigned* __restrict__ offsets, const unsigned short* __restrict__ esrc,
                const unsigned short* __restrict__ T16, const unsigned* __restrict__ flags,
                void* __restrict__ outv) {
    const unsigned fp32mode = flags[0];
    const int lane = threadIdx.x & 63;
    const int wid  = threadIdx.x >> 6;
    const int n = (blockIdx.x << 2) + wid;             // grid exact: 12500*4 waves
    const int g  = lane >> 4;
    const int fb = (lane & 15) << 2;
    const int a = (int)offsets[n];
    const int b = (int)offsets[n + 1];
    const float FMAX = __uint_as_float(0x7f7fffffu);
    float m0 = FMAX, m1 = FMAX, m2 = FMAX, m3 = FMAX;

    int i = a + g;
    for (; i + 4 < b; i += 8) {                        // 2 gathers in flight
        int s0 = (int)esrc[i], s1 = (int)esrc[i + 4];
        uint2 v0 = *(const uint2*)(T16 + s0 * D + fb);
        uint2 v1 = *(const uint2*)(T16 + s1 * D + fb);
        m0 = fminf(m0, fminf(b2f((unsigned short)v0.x), b2f((unsigned short)v1.x)));
        m1 = fminf(m1, fminf(b2f((unsigned short)(v0.x >> 16)), b2f((unsigned short)(v1.x >> 16))));
        m2 = fminf(m2, fminf(b2f((unsigned short)v0.y), b2f((unsigned short)v1.y)));
        m3 = fminf(m3, fminf(b2f((unsigned short)(v0.y >> 16)), b2f((unsigned short)(v1.y >> 16))));
    }
    if (i < b) {
        int s0 = (int)esrc[i];
        uint2 v0 = *(const uint2*)(T16 + s0 * D + fb);
        m0 = fminf(m0, b2f((unsigned short)v0.x));
        m1 = fminf(m1, b2f((unsigned short)(v0.x >> 16)));
        m2 = fminf(m2, b2f((unsigned short)v0.y));
        m3 = fminf(m3, b2f((unsigned short)(v0.y >> 16)));
    }
    // combine the 4 edge-groups: lanes l, l^16, l^32, l^48 share features
    m0 = fminf(m0, __shfl_xor(m0, 16, 64)); m0 = fminf(m0, __shfl_xor(m0, 32, 64));
    m1 = fminf(m1, __shfl_xor(m1, 16, 64)); m1 = fminf(m1, __shfl_xor(m1, 32, 64));
    m2 = fminf(m2, __shfl_xor(m2, 16, 64)); m2 = fminf(m2, __shfl_xor(m2, 32, 64));
    m3 = fminf(m3, __shfl_xor(m3, 16, 64)); m3 = fminf(m3, __shfl_xor(m3, 32, 64));
    if (lane < 16) {
        if (fp32mode) {
            float* C = (float*)outv + n * D + fb;
            float4 c = *(const float4*)C;
            *(float4*)C = make_float4(c.x - m0, c.y - m1, c.z - m2, c.w - m3);
        } else {
            unsigned short* C = (unsigned short*)outv + n * D + fb;
            uint2 c = *(const uint2*)C;
            unsigned lo = (unsigned)f2b(b2f((unsigned short)c.x) - m0)
                        | ((unsigned)f2b(b2f((unsigned short)(c.x >> 16)) - m1) << 16);
            unsigned hi = (unsigned)f2b(b2f((unsigned short)c.y) - m2)
                        | ((unsigned)f2b(b2f((unsigned short)(c.y >> 16)) - m3) << 16);
            *(uint2*)C = make_uint2(lo, hi);
        }
    }
}

extern "C" void kernel_launch(void* const* d_in, const int* in_sizes, int n_in,
                              void* d_out, int out_size, void* d_ws, size_t ws_size,
                              hipStream_t stream) {
    // ws layout (~11.4 MB; known-safe budget <= 12.8 MB):
    char* p = (char*)d_ws;
    unsigned*       flags   = (unsigned*)p;                      // 256 B
    unsigned*       offsets = (unsigned*)(p + 256);              // 50017*4 -> pad 200320
    unsigned*       c_cnt   = (unsigned*)(p + 256 + 200320);     // 1024
    unsigned*       c_off   = (unsigned*)(p + 256 + 201344);     // 1024
    unsigned*       c_cur   = (unsigned*)(p + 256 + 202368);     // 1024
    unsigned*       packed  = (unsigned*)(p + 256 + 203392);     // 3.2 MB
    unsigned short* esrc    = (unsigned short*)(p + 256 + 203392 + 3200000);  // 1.6 MB
    unsigned short* T16     = (unsigned short*)(p + 256 + 203392 + 3200000 + 1600000); // 6.4 MB

    detect_mode<<<1, 128, 0, stream>>>(d_in[0], d_in[1], flags);
    node_both<<<256, 256, 0, stream>>>(d_in[0], d_in[3], d_in[4],
                                       d_in[5], d_in[6], flags, T16, d_out);
    hipMemsetAsync(c_cnt, 0, NB * sizeof(unsigned), stream);
    coarse_count<<<NPB, 256, 0, stream>>>(d_in[2], flags, c_cnt);
    scanNB<<<1, 256, 0, stream>>>(c_cnt, c_off, c_cur, offsets);
    coarse_scatter<<<NPB, 256, 0, stream>>>(d_in[1], d_in[2], flags, c_cur, packed);
    bucket_build<<<NB, 256, 0, stream>>>(c_off, packed, offsets, esrc);
    min_gather<<<N_NODES / 4, 256, 0, stream>>>(offsets, esrc, T16, flags, d_out);
}